// Round 1
// baseline (32790.759 us; speedup 1.0000x reference)
//
#include <hip/hip_runtime.h>
#include <cstdint>
#include <cstddef>

// Problem constants
#define B_ 64
#define S_ 2048
#define F_ 128
#define H_ 512
#define HO1 16777216ull
#define CO1 16809984ull
#define HO2 16842752ull
#define CO2 16875520ull

typedef __bf16 bf16_t;
typedef __attribute__((ext_vector_type(8))) __bf16 bf16x8;
typedef __attribute__((ext_vector_type(4))) float f32x4;
typedef __attribute__((ext_vector_type(8))) unsigned short u16x8;
typedef __attribute__((ext_vector_type(4))) unsigned int u32x4;

// ---- workspace layout (bytes) ---- (sizes identical to previous version)
#define OFF_ARR   0ull        // arrival flags: [4 groups][64 WGs] u32
#define OFF_PG    2048ull     // prev_gen0 bf16 [64][128]
#define OFF_H1    18432ull    // h1 double buffer bf16, slab-packed [2][64 slabs][64 rows][8]
#define OFF_H2    149504ull   // h2 double buffer, slab-packed
#define OFF_OUT   280576ull   // fc1 'out' bf16, slab-packed [64][64][8]
#define OFF_B1P   346112ull   // fused bias1' fp32 [512]
#define OFF_WF    348160ull   // Wfused fp32 [512][512]
#define OFF_FRAG  1396736ull  // fragment heap (9984 frags x 1KiB)
#define FR_S2   0
#define FR_S3   4096
#define FR_S1   8192
#define FR_S1T0 9472
#define FR_TOTAL 9984

// slab-packed exchange layout: elem index of (slab=col/8, row b, j=col%8)
#define XIDX(s, b) (((size_t)((s) * 64 + (b))) * 8)

__device__ __forceinline__ float sigm(float x) { return 1.f / (1.f + __expf(-x)); }
__device__ __forceinline__ float tanh_(float x) { return 2.f / (1.f + __expf(-2.f * x)) - 1.f; }

struct U128 { unsigned long long a, b; };

// cache-bypassing (fabric-coherent) 16B slab load: two 8B relaxed agent atomics.
__device__ __forceinline__ bf16x8 ld_slab(const bf16_t* p) {
    unsigned long long* q = (unsigned long long*)p;
    U128 u;
    u.a = __hip_atomic_load(q, __ATOMIC_RELAXED, __HIP_MEMORY_SCOPE_AGENT);
    u.b = __hip_atomic_load(q + 1, __ATOMIC_RELAXED, __HIP_MEMORY_SCOPE_AGENT);
    return __builtin_bit_cast(bf16x8, u);
}

// ---------------- prep: init flags + small buffers ----------------
__global__ void k_init(const float* __restrict__ pg0, const float* __restrict__ h1i,
                       const float* __restrict__ h2i, uint8_t* __restrict__ ws) {
    int idx = blockIdx.x * 256 + threadIdx.x;
    if (idx < 512) ((unsigned int*)ws)[idx] = 0u;  // arrival flags
    if (idx < B_ * F_) ((bf16_t*)(ws + OFF_PG))[idx] = (bf16_t)pg0[idx];
    if (idx < B_ * H_) {
        int b = idx >> 9, col = idx & 511;
        size_t d = XIDX(col >> 3, b) + (col & 7);           // slab-packed
        ((bf16_t*)(ws + OFF_H1))[B_ * H_ + d] = (bf16_t)h1i[idx];  // buffer 1 = "t=-1"
        ((bf16_t*)(ws + OFF_H2))[B_ * H_ + d] = (bf16_t)h2i[idx];
    }
}

// ---------------- prep: Wfused = W_fc1[:,128:256] @ W_fc2  (and bias1') ----------------
__global__ void k_fuse(const float* __restrict__ Wfc1, const float* __restrict__ bfc1,
                       const float* __restrict__ Wfc2, const float* __restrict__ bfc2,
                       uint8_t* __restrict__ ws) {
    int o = blockIdx.x;      // 0..511
    int t = threadIdx.x;     // 0..127
    __shared__ float wrow[128];
    wrow[t] = Wfc1[o * 256 + 128 + t];
    __syncthreads();
    float* WF = (float*)(ws + OFF_WF);
    f32x4 s = {0.f, 0.f, 0.f, 0.f};
    for (int m = 0; m < 128; ++m) {
        f32x4 b = *(const f32x4*)(Wfc2 + m * 512 + t * 4);
        float w = wrow[m];
        s[0] += w * b[0]; s[1] += w * b[1]; s[2] += w * b[2]; s[3] += w * b[3];
    }
    *(f32x4*)(WF + o * 512 + t * 4) = s;
    if (t == 0) {
        float sb = bfc1[o];
        for (int m = 0; m < 128; ++m) sb += wrow[m] * bfc2[m];
        ((float*)(ws + OFF_B1P))[o] = sb;
    }
}

// ---------------- prep: build MFMA B-fragments for all stages ----------------
__global__ void k_frags(const float* __restrict__ Wfc1, const float* __restrict__ Wih1,
                        const float* __restrict__ Whh1, const float* __restrict__ Wih2,
                        const float* __restrict__ Whh2, const float* __restrict__ Wfc2,
                        uint8_t* __restrict__ ws) {
    int gid = blockIdx.x * 256 + threadIdx.x;  // exactly FR_TOTAL*64 threads
    int fid = gid >> 6;
    int lane = gid & 63;
    int n16 = lane & 15, quad = lane >> 4;
    const float* WF = (const float*)(ws + OFF_WF);
    u16x8 pk;
#pragma unroll
    for (int j = 0; j < 8; ++j) {
        float v = 0.f;
        if (fid < 4096) {  // stage2 (LSTM1): in=[out|h1] K=1024, 32 gate-cols per WG
            int tl = fid & 1, ki = (fid >> 1) & 7, wv = (fid >> 4) & 3, wg = fid >> 6;
            int n32 = tl * 16 + n16; int j8 = n32 & 7; int gate = n32 >> 3;
            int R = gate * 512 + wg * 8 + j8;
            int k = wv * 256 + ki * 32 + quad * 8 + j;
            v = (k < 512) ? Wih1[R * 512 + k] : Whh1[R * 512 + k - 512];
        } else if (fid < 8192) {  // stage3 (LSTM2): in=[h1n|h2]
            int f2 = fid - 4096;
            int tl = f2 & 1, ki = (f2 >> 1) & 7, wv = (f2 >> 4) & 3, wg = f2 >> 6;
            int n32 = tl * 16 + n16; int j8 = n32 & 7; int gate = n32 >> 3;
            int R = gate * 512 + wg * 8 + j8;
            int k = wv * 256 + ki * 32 + quad * 8 + j;
            v = (k < 512) ? Wih2[R * 512 + k] : Whh2[R * 512 + k - 512];
        } else if (fid < 9472) {  // stage1 fused (t>=1): in=[x|h2p] K=640, cols=[out(8)|gen(2)|pad]
            int f2 = fid - 8192;
            int ki = f2 % 5; int wv = (f2 / 5) & 3; int wg = f2 / 20;
            int k = wv * 160 + ki * 32 + quad * 8 + j;
            if (n16 < 8) {
                int o = wg * 8 + n16;
                v = (k < 128) ? Wfc1[o * 256 + k] : WF[o * 512 + (k - 128)];
            } else if (n16 < 10) {
                int m = wg * 2 + (n16 - 8);
                v = (k < 128) ? 0.f : Wfc2[m * 512 + (k - 128)];
            }
        } else {  // stage1 at t==0: in=[x0|prev_gen0] K=256, W_fc1 direct
            int f2 = fid - 9472;
            int ki = f2 & 1; int wv = (f2 >> 1) & 3; int wg = f2 >> 3;
            int k = wv * 64 + ki * 32 + quad * 8 + j;
            if (n16 < 8) v = Wfc1[(wg * 8 + n16) * 256 + k];
        }
        bf16_t bb = (bf16_t)v;
        pk[j] = __builtin_bit_cast(unsigned short, bb);
    }
    *((u16x8*)(ws + OFF_FRAG) + (size_t)fid * 64 + lane) = pk;
}

// ---------------- barrier: packed arrive + low-transaction wait ----------------
// arrive_pack: one syncthreads makes LDS hbuf visible; wave0 lanes 0..15 emit the
// WG's whole 256B h-slice as 16 contiguous dwordx4 stores (sc0 sc1), wave0 drains
// its own vmcnt, tid0 publishes the flag. Only wave0 carries protocol stores.
__device__ __forceinline__ void arrive_pack(unsigned int* arr, int wg, int tid,
                                            unsigned int tgt, bf16_t* dst,
                                            const unsigned short* hb) {
    __syncthreads();
    if (tid < 64) {
        if (tid < 16) {
            u32x4 v = *(const u32x4*)(hb + tid * 8);  // LDS row (16B)
            asm volatile("global_store_dwordx4 %0, %1, off sc0 sc1"
                         :: "v"(dst + (size_t)tid * 8), "v"(v) : "memory");
        }
        asm volatile("s_waitcnt vmcnt(0)" ::: "memory");
        if (tid == 0)
            __hip_atomic_store(arr + wg, tgt, __ATOMIC_RELAXED, __HIP_MEMORY_SCOPE_AGENT);
    }
}

// wait: 16 lanes each poll 4 flags with one dwordx4 (4 cachelines total vs 64
// scattered dwords before). __all over the 16 active lanes.
__device__ __forceinline__ void bar_wait(const unsigned int* arr, int tid, unsigned int tgt) {
    if (tid < 16) {
        const unsigned int* p = arr + tid * 4;
        while (true) {
            u32x4 f;
            asm volatile("global_load_dwordx4 %0, %1, off sc0 sc1\n\ts_waitcnt vmcnt(0)"
                         : "=&v"(f) : "v"(p) : "memory");
            if (__all(f[0] >= tgt && f[1] >= tgt && f[2] >= tgt && f[3] >= tgt)) break;
        }
    }
    __syncthreads();
}

// ---------------- persistent recurrence kernel ----------------
__launch_bounds__(256, 1)
__global__ void k_rnn(const float* __restrict__ x, const float* __restrict__ c1i,
                      const float* __restrict__ c2i, const float* __restrict__ bfc1,
                      const float* __restrict__ b1, const float* __restrict__ b2g,
                      const float* __restrict__ bfc2, uint8_t* __restrict__ ws,
                      float* __restrict__ out) {
    const int wg = blockIdx.x & 63;
    const int g = blockIdx.x >> 6;
    const int tid = threadIdx.x;
    const int wave = tid >> 6, lane = tid & 63;
    const int quad = lane >> 4, row16 = lane & 15;
    const int brow = g * 16 + row16;

    bf16_t* pg = (bf16_t*)(ws + OFF_PG);
    bf16_t* h1b = (bf16_t*)(ws + OFF_H1);
    bf16_t* h2b = (bf16_t*)(ws + OFF_H2);
    bf16_t* outb = (bf16_t*)(ws + OFF_OUT);
    const float* b1p = (const float*)(ws + OFF_B1P);
    unsigned int* arr = (unsigned int*)(ws + OFF_ARR) + g * 64;
    const u16x8* heap = (const u16x8*)(ws + OFF_FRAG);

    // ---- load all weight fragments into registers (stationary for all 2048 steps) ----
    bf16x8 fr2[16], fr3[16], fr1[5], fr10[2];
    const int wslot = wg * 4 + wave;
#pragma unroll
    for (int f = 0; f < 16; ++f)
        fr2[f] = __builtin_bit_cast(bf16x8, heap[(size_t)(FR_S2 + wslot * 16 + f) * 64 + lane]);
#pragma unroll
    for (int f = 0; f < 16; ++f)
        fr3[f] = __builtin_bit_cast(bf16x8, heap[(size_t)(FR_S3 + wslot * 16 + f) * 64 + lane]);
#pragma unroll
    for (int f = 0; f < 5; ++f)
        fr1[f] = __builtin_bit_cast(bf16x8, heap[(size_t)(FR_S1 + wslot * 5 + f) * 64 + lane]);
#pragma unroll
    for (int f = 0; f < 2; ++f)
        fr10[f] = __builtin_bit_cast(bf16x8, heap[(size_t)(FR_S1T0 + wslot * 2 + f) * 64 + lane]);

    __shared__ float red[4][2][16][17];               // +1 pad: breaks 4-way quad aliasing
    __shared__ alignas(16) unsigned short hbuf[16][8];  // packed h slice (bf16 bits)

    // per-thread (rrow, rc) covers the 16x16 D-tile
    const int rrow = tid >> 4, rc = tid & 15;
    const float bias2_a = b1[(rc >> 3) * 512 + wg * 8 + (rc & 7)];
    const float bias2_b = b1[(2 + (rc >> 3)) * 512 + wg * 8 + (rc & 7)];
    const float bias3_a = b2g[(rc >> 3) * 512 + wg * 8 + (rc & 7)];
    const float bias3_b = b2g[(2 + (rc >> 3)) * 512 + wg * 8 + (rc & 7)];
    const float bias1 = (rc < 8) ? b1p[wg * 8 + rc] : ((rc < 10) ? bfc2[wg * 2 + rc - 8] : 0.f);
    const float bias1t0 = (rc < 8) ? bfc1[wg * 8 + rc] : 0.f;

    // cell state: one fp32 per owning thread (rc<8), lives in registers all 2048 steps
    float c1r = 0.f, c2r = 0.f;
    if (rc < 8) {
        c1r = c1i[(size_t)(g * 16 + rrow) * H_ + wg * 8 + rc];
        c2r = c2i[(size_t)(g * 16 + rrow) * H_ + wg * 8 + rc];
    }

    unsigned int bt = 0;
    bf16x8 xpre[4];  // x(t) bf16 prefetch, wave0 only

#pragma clang loop unroll(disable)
    for (int t = 0; t <= S_; ++t) {
        const int cbuf = t & 1, pbuf = cbuf ^ 1;
        bf16x8 pre2[8], pre3[8];  // stale-operand prefetch (waves 2-3)

        // ============ P1: out = relu([x_t | h2p] @ W1') ; gen(t-1) = extra cols ============
        if (t > 0) bar_wait(arr, tid, bt);  // P3(t-1) done -> h2(t-1) visible
        {
            f32x4 acc = {0.f, 0.f, 0.f, 0.f};
            if (t == 0) {
#pragma unroll
                for (int ki = 0; ki < 2; ++ki) {
                    int k = wave * 64 + ki * 32 + quad * 8;
                    bf16x8 a;
                    if (k < 128) {
                        const float* xp = x + ((size_t)brow * S_) * F_ + k;
                        f32x4 x0 = *(const f32x4*)xp, x1 = *(const f32x4*)(xp + 4);
#pragma unroll
                        for (int i = 0; i < 4; ++i) { a[i] = (bf16_t)x0[i]; a[4 + i] = (bf16_t)x1[i]; }
                    } else {
                        a = *(const bf16x8*)(pg + (size_t)brow * 128 + (k - 128));
                    }
                    acc = __builtin_amdgcn_mfma_f32_16x16x32_bf16(a, fr10[ki], acc, 0, 0, 0);
                }
            } else {
                const bf16_t* h2p = h2b + (size_t)pbuf * (B_ * H_);
#pragma unroll
                for (int ki = 0; ki < 5; ++ki) {
                    int k = wave * 160 + ki * 32 + quad * 8;
                    bf16x8 a;
                    if (wave == 0 && ki < 4) a = xpre[ki];  // prefetched last step
                    else a = ld_slab(h2p + XIDX((k - 128) >> 3, brow));
                    acc = __builtin_amdgcn_mfma_f32_16x16x32_bf16(a, fr1[ki], acc, 0, 0, 0);
                }
            }
#pragma unroll
            for (int i = 0; i < 4; ++i) red[wave][0][quad * 4 + i][row16] = acc[i];
            __syncthreads();
            float v = red[0][0][rrow][rc] + red[1][0][rrow][rc] + red[2][0][rrow][rc] +
                      red[3][0][rrow][rc];
            if (t < S_) {
                if (rc < 8) {
                    float vv = fmaxf(v + (t == 0 ? bias1t0 : bias1), 0.f);
                    hbuf[rrow][rc] = __builtin_bit_cast(unsigned short, (bf16_t)vv);
                }
                arrive_pack(arr, wg, tid, ++bt, outb + XIDX(wg, g * 16), &hbuf[0][0]);
            }
            if (t > 0 && rc >= 8 && rc < 10) {  // gen(t-1) -> d_out (fp32), off critical path
                out[(size_t)(g * 16 + rrow) * (S_ * F_) + (size_t)(t - 1) * F_ + wg * 2 + (rc - 8)] =
                    v + bias1;
            }
        }
        if (t == S_) break;  // last gen written; done
        // prefetch h1(t-1) (stale, visible since P2(t-1)) while polling
        if (wave >= 2) {
            const bf16_t* h1p = h1b + (size_t)pbuf * (B_ * H_);
#pragma unroll
            for (int ki = 0; ki < 8; ++ki)
                pre2[ki] = ld_slab(h1p + XIDX((wave - 2) * 32 + ki * 4 + quad, brow));
        }
        bar_wait(arr, tid, bt);

        // ============ P2: LSTM1 gates = [out | h1(t-1)] @ W ; update c1, h1n ============
        {
            f32x4 acc0 = {0.f, 0.f, 0.f, 0.f}, acc1 = {0.f, 0.f, 0.f, 0.f};
            if (wave < 2) {
#pragma unroll
                for (int ki = 0; ki < 8; ++ki) {
                    bf16x8 a = ld_slab(outb + XIDX(wave * 32 + ki * 4 + quad, brow));
                    acc0 = __builtin_amdgcn_mfma_f32_16x16x32_bf16(a, fr2[ki * 2 + 0], acc0, 0, 0, 0);
                    acc1 = __builtin_amdgcn_mfma_f32_16x16x32_bf16(a, fr2[ki * 2 + 1], acc1, 0, 0, 0);
                }
            } else {
#pragma unroll
                for (int ki = 0; ki < 8; ++ki) {
                    acc0 = __builtin_amdgcn_mfma_f32_16x16x32_bf16(pre2[ki], fr2[ki * 2 + 0], acc0, 0, 0, 0);
                    acc1 = __builtin_amdgcn_mfma_f32_16x16x32_bf16(pre2[ki], fr2[ki * 2 + 1], acc1, 0, 0, 0);
                }
            }
#pragma unroll
            for (int i = 0; i < 4; ++i) {
                red[wave][0][quad * 4 + i][row16] = acc0[i];
                red[wave][1][quad * 4 + i][row16] = acc1[i];
            }
            __syncthreads();
            float v0 = red[0][0][rrow][rc] + red[1][0][rrow][rc] + red[2][0][rrow][rc] +
                       red[3][0][rrow][rc] + bias2_a;   // i (rc<8) | f (rc>=8)
            float v1 = red[0][1][rrow][rc] + red[1][1][rrow][rc] + red[2][1][rrow][rc] +
                       red[3][1][rrow][rc] + bias2_b;   // g (rc<8) | o (rc>=8)
            float f0 = __shfl_down(v0, 8);  // f gate for rc<8
            float f1 = __shfl_down(v1, 8);  // o gate for rc<8
            if (rc < 8) {
                float cn = sigm(f0) * c1r + sigm(v0) * tanh_(v1);
                c1r = cn;
                float h = sigm(f1) * tanh_(cn);
                hbuf[rrow][rc] = __builtin_bit_cast(unsigned short, (bf16_t)h);
                if (t == S_ - 1) {
                    out[HO1 + (size_t)(g * 16 + rrow) * H_ + wg * 8 + rc] = h;
                    out[CO1 + (size_t)(g * 16 + rrow) * H_ + wg * 8 + rc] = cn;
                }
            }
        }
        arrive_pack(arr, wg, tid, ++bt,
                    h1b + (size_t)cbuf * (B_ * H_) + XIDX(wg, g * 16), &hbuf[0][0]);
        // prefetch h2(t-1) (stale, visible since P3(t-1)) while polling
        if (wave >= 2) {
            const bf16_t* h2p = h2b + (size_t)pbuf * (B_ * H_);
#pragma unroll
            for (int ki = 0; ki < 8; ++ki)
                pre3[ki] = ld_slab(h2p + XIDX((wave - 2) * 32 + ki * 4 + quad, brow));
        }
        bar_wait(arr, tid, bt);

        // ============ P3: LSTM2 gates = [h1n | h2(t-1)] @ W ; update c2, h2n ============
        {
            f32x4 acc0 = {0.f, 0.f, 0.f, 0.f}, acc1 = {0.f, 0.f, 0.f, 0.f};
            if (wave < 2) {
                const bf16_t* h1c = h1b + (size_t)cbuf * (B_ * H_);
#pragma unroll
                for (int ki = 0; ki < 8; ++ki) {
                    bf16x8 a = ld_slab(h1c + XIDX(wave * 32 + ki * 4 + quad, brow));
                    acc0 = __builtin_amdgcn_mfma_f32_16x16x32_bf16(a, fr3[ki * 2 + 0], acc0, 0, 0, 0);
                    acc1 = __builtin_amdgcn_mfma_f32_16x16x32_bf16(a, fr3[ki * 2 + 1], acc1, 0, 0, 0);
                }
            } else {
#pragma unroll
                for (int ki = 0; ki < 8; ++ki) {
                    acc0 = __builtin_amdgcn_mfma_f32_16x16x32_bf16(pre3[ki], fr3[ki * 2 + 0], acc0, 0, 0, 0);
                    acc1 = __builtin_amdgcn_mfma_f32_16x16x32_bf16(pre3[ki], fr3[ki * 2 + 1], acc1, 0, 0, 0);
                }
            }
#pragma unroll
            for (int i = 0; i < 4; ++i) {
                red[wave][0][quad * 4 + i][row16] = acc0[i];
                red[wave][1][quad * 4 + i][row16] = acc1[i];
            }
            __syncthreads();
            float v0 = red[0][0][rrow][rc] + red[1][0][rrow][rc] + red[2][0][rrow][rc] +
                       red[3][0][rrow][rc] + bias3_a;
            float v1 = red[0][1][rrow][rc] + red[1][1][rrow][rc] + red[2][1][rrow][rc] +
                       red[3][1][rrow][rc] + bias3_b;
            float f0 = __shfl_down(v0, 8);
            float f1 = __shfl_down(v1, 8);
            if (rc < 8) {
                float cn = sigm(f0) * c2r + sigm(v0) * tanh_(v1);
                c2r = cn;
                float h = sigm(f1) * tanh_(cn);
                hbuf[rrow][rc] = __builtin_bit_cast(unsigned short, (bf16_t)h);
                if (t == S_ - 1) {
                    out[HO2 + (size_t)(g * 16 + rrow) * H_ + wg * 8 + rc] = h;
                    out[CO2 + (size_t)(g * 16 + rrow) * H_ + wg * 8 + rc] = cn;
                }
            }
        }
        arrive_pack(arr, wg, tid, ++bt,
                    h2b + (size_t)cbuf * (B_ * H_) + XIDX(wg, g * 16), &hbuf[0][0]);
        // prefetch x(t+1) while polling (plain cached loads — x is read-only input)
        if (wave == 0) {
            const int tn = (t + 1 < S_) ? (t + 1) : (S_ - 1);
            const float* xp = x + ((size_t)brow * S_ + tn) * F_ + quad * 8;
#pragma unroll
            for (int ki = 0; ki < 4; ++ki) {
                f32x4 x0 = *(const f32x4*)(xp + ki * 32);
                f32x4 x1 = *(const f32x4*)(xp + ki * 32 + 4);
                bf16x8 a;
#pragma unroll
                for (int i = 0; i < 4; ++i) { a[i] = (bf16_t)x0[i]; a[4 + i] = (bf16_t)x1[i]; }
                xpre[ki] = a;
            }
        }
        // loop head does bar_wait(bt) -> P1 of t+1
    }
}

extern "C" void kernel_launch(void* const* d_in, const int* in_sizes, int n_in, void* d_out,
                              int out_size, void* d_ws, size_t ws_size, hipStream_t stream) {
    const float* x = (const float*)d_in[0];
    const float* pg0 = (const float*)d_in[1];
    const float* h1i = (const float*)d_in[2];
    const float* c1i = (const float*)d_in[3];
    const float* h2i = (const float*)d_in[4];
    const float* c2i = (const float*)d_in[5];
    const float* Wfc1 = (const float*)d_in[6];
    const float* bfc1 = (const float*)d_in[7];
    const float* Wih1 = (const float*)d_in[8];
    const float* Whh1 = (const float*)d_in[9];
    const float* b1 = (const float*)d_in[10];
    const float* Wih2 = (const float*)d_in[11];
    const float* Whh2 = (const float*)d_in[12];
    const float* b2g = (const float*)d_in[13];
    const float* Wfc2 = (const float*)d_in[14];
    const float* bfc2 = (const float*)d_in[15];
    uint8_t* ws = (uint8_t*)d_ws;
    float* out = (float*)d_out;

    k_init<<<dim3(128), dim3(256), 0, stream>>>(pg0, h1i, h2i, ws);
    k_fuse<<<dim3(512), dim3(128), 0, stream>>>(Wfc1, bfc1, Wfc2, bfc2, ws);
    k_frags<<<dim3(2496), dim3(256), 0, stream>>>(Wfc1, Wih1, Whh1, Wih2, Whh2, Wfc2, ws);
    k_rnn<<<dim3(256), dim3(256), 0, stream>>>(x, c1i, c2i, bfc1, b1, b2g, bfc2, ws, out);
}

// Round 2
// 27719.940 us; speedup vs baseline: 1.1829x; 1.1829x over previous
//
#include <hip/hip_runtime.h>
#include <cstdint>
#include <cstddef>

// Problem constants
#define B_ 64
#define S_ 2048
#define F_ 128
#define H_ 512
#define HO1 16777216ull
#define CO1 16809984ull
#define HO2 16842752ull
#define CO2 16875520ull
#define BH (B_ * H_)

typedef __bf16 bf16_t;
typedef __attribute__((ext_vector_type(8))) __bf16 bf16x8;
typedef __attribute__((ext_vector_type(4))) float f32x4;
typedef __attribute__((ext_vector_type(8))) unsigned short u16x8;

// ---- workspace layout (bytes) ----
#define OFF_PG    2048ull     // prev_gen0 bf16 [64][128]
#define OFF_H1    18432ull    // h1 double buffer bf16, slab-packed [2][64 slabs][64 rows][8]
#define OFF_H2    149504ull   // h2 double buffer, slab-packed
#define OFF_OUT   280576ull   // fc1 'out' bf16, slab-packed [64][64][8]
#define OFF_B1P   346112ull   // fused bias1' fp32 [512]
#define OFF_WF    348160ull   // Wfused fp32 [512][512]
#define OFF_FRAG  1396736ull  // fragment heap (9984 frags x 1KiB)
#define FR_S2   0
#define FR_S3   4096
#define FR_S1   8192
#define FR_S1T0 9472
#define FR_TOTAL 9984

// slab-packed exchange layout: elem index of (slab=col/8, row b, j=col%8)
#define XIDX(s, b) (((size_t)((s) * 64 + (b))) * 8)

__device__ __forceinline__ float sigm(float x) { return 1.f / (1.f + __expf(-x)); }
__device__ __forceinline__ float tanh_(float x) { return 2.f / (1.f + __expf(-2.f * x)) - 1.f; }

struct U128 { unsigned long long a, b; };

// cache-bypassing (fabric-coherent) 16B slab load: two 8B relaxed agent atomics.
__device__ __forceinline__ bf16x8 ld_slab(const bf16_t* p) {
    unsigned long long* q = (unsigned long long*)p;
    U128 u;
    u.a = __hip_atomic_load(q, __ATOMIC_RELAXED, __HIP_MEMORY_SCOPE_AGENT);
    u.b = __hip_atomic_load(q + 1, __ATOMIC_RELAXED, __HIP_MEMORY_SCOPE_AGENT);
    return __builtin_bit_cast(bf16x8, u);
}

__device__ __forceinline__ void st_bf16(bf16_t* p, float v) {
    bf16_t b = (bf16_t)v;
    __hip_atomic_store((unsigned short*)p, __builtin_bit_cast(unsigned short, b),
                       __ATOMIC_RELAXED, __HIP_MEMORY_SCOPE_AGENT);
}

__device__ __forceinline__ void st_poison(bf16_t* p) {
    __hip_atomic_store((unsigned short*)p, (unsigned short)0xFFFFu,
                       __ATOMIC_RELAXED, __HIP_MEMORY_SCOPE_AGENT);
}

// data IS the flag: 0xFFFF (bf16 NaN) marks not-yet-written. Real h/out values
// (finite float -> bf16) can never be 0xFFFF.
__device__ __forceinline__ int ok8(bf16x8 a) {
    u16x8 u = __builtin_bit_cast(u16x8, a);
    int bad = 0;
#pragma unroll
    for (int i = 0; i < 8; ++i) bad |= (u[i] == 0xFFFFu) ? 1 : 0;
    return !bad;
}

// ---------------- prep: init small buffers + poison exchange buffers ----------------
__global__ void k_init(const float* __restrict__ pg0, const float* __restrict__ h1i,
                       const float* __restrict__ h2i, uint8_t* __restrict__ ws) {
    int idx = blockIdx.x * 256 + threadIdx.x;
    if (idx < B_ * F_) ((bf16_t*)(ws + OFF_PG))[idx] = (bf16_t)pg0[idx];
    if (idx < B_ * H_) {
        int b = idx >> 9, col = idx & 511;
        size_t d = XIDX(col >> 3, b) + (col & 7);  // slab-packed
        unsigned short* h1 = (unsigned short*)(ws + OFF_H1);
        unsigned short* h2 = (unsigned short*)(ws + OFF_H2);
        unsigned short* ob = (unsigned short*)(ws + OFF_OUT);
        bf16_t v1 = (bf16_t)h1i[idx], v2 = (bf16_t)h2i[idx];
        h1[0 * BH + d] = 0xFFFFu;                                // buffer 0: poisoned
        h1[1 * BH + d] = __builtin_bit_cast(unsigned short, v1); // buffer 1 = "t=-1"
        h2[0 * BH + d] = 0xFFFFu;
        h2[1 * BH + d] = __builtin_bit_cast(unsigned short, v2);
        ob[d] = 0xFFFFu;                                          // outb: poisoned
    }
}

// ---------------- prep: Wfused = W_fc1[:,128:256] @ W_fc2  (and bias1') ----------------
__global__ void k_fuse(const float* __restrict__ Wfc1, const float* __restrict__ bfc1,
                       const float* __restrict__ Wfc2, const float* __restrict__ bfc2,
                       uint8_t* __restrict__ ws) {
    int o = blockIdx.x;      // 0..511
    int t = threadIdx.x;     // 0..127
    __shared__ float wrow[128];
    wrow[t] = Wfc1[o * 256 + 128 + t];
    __syncthreads();
    float* WF = (float*)(ws + OFF_WF);
    f32x4 s = {0.f, 0.f, 0.f, 0.f};
    for (int m = 0; m < 128; ++m) {
        f32x4 b = *(const f32x4*)(Wfc2 + m * 512 + t * 4);
        float w = wrow[m];
        s[0] += w * b[0]; s[1] += w * b[1]; s[2] += w * b[2]; s[3] += w * b[3];
    }
    *(f32x4*)(WF + o * 512 + t * 4) = s;
    if (t == 0) {
        float sb = bfc1[o];
        for (int m = 0; m < 128; ++m) sb += wrow[m] * bfc2[m];
        ((float*)(ws + OFF_B1P))[o] = sb;
    }
}

// ---------------- prep: build MFMA B-fragments for all stages ----------------
__global__ void k_frags(const float* __restrict__ Wfc1, const float* __restrict__ Wih1,
                        const float* __restrict__ Whh1, const float* __restrict__ Wih2,
                        const float* __restrict__ Whh2, const float* __restrict__ Wfc2,
                        uint8_t* __restrict__ ws) {
    int gid = blockIdx.x * 256 + threadIdx.x;  // exactly FR_TOTAL*64 threads
    int fid = gid >> 6;
    int lane = gid & 63;
    int n16 = lane & 15, quad = lane >> 4;
    const float* WF = (const float*)(ws + OFF_WF);
    u16x8 pk;
#pragma unroll
    for (int j = 0; j < 8; ++j) {
        float v = 0.f;
        if (fid < 4096) {  // stage2 (LSTM1): in=[out|h1] K=1024, 32 gate-cols per WG
            int tl = fid & 1, ki = (fid >> 1) & 7, wv = (fid >> 4) & 3, wg = fid >> 6;
            int n32 = tl * 16 + n16; int j8 = n32 & 7; int gate = n32 >> 3;
            int R = gate * 512 + wg * 8 + j8;
            int k = wv * 256 + ki * 32 + quad * 8 + j;
            v = (k < 512) ? Wih1[R * 512 + k] : Whh1[R * 512 + k - 512];
        } else if (fid < 8192) {  // stage3 (LSTM2): in=[h1n|h2]
            int f2 = fid - 4096;
            int tl = f2 & 1, ki = (f2 >> 1) & 7, wv = (f2 >> 4) & 3, wg = f2 >> 6;
            int n32 = tl * 16 + n16; int j8 = n32 & 7; int gate = n32 >> 3;
            int R = gate * 512 + wg * 8 + j8;
            int k = wv * 256 + ki * 32 + quad * 8 + j;
            v = (k < 512) ? Wih2[R * 512 + k] : Whh2[R * 512 + k - 512];
        } else if (fid < 9472) {  // stage1 fused (t>=1): in=[x|h2p] K=640, cols=[out(8)|gen(2)|pad]
            int f2 = fid - 8192;
            int ki = f2 % 5; int wv = (f2 / 5) & 3; int wg = f2 / 20;
            int k = wv * 160 + ki * 32 + quad * 8 + j;
            if (n16 < 8) {
                int o = wg * 8 + n16;
                v = (k < 128) ? Wfc1[o * 256 + k] : WF[o * 512 + (k - 128)];
            } else if (n16 < 10) {
                int m = wg * 2 + (n16 - 8);
                v = (k < 128) ? 0.f : Wfc2[m * 512 + (k - 128)];
            }
        } else {  // stage1 at t==0: in=[x0|prev_gen0] K=256, W_fc1 direct
            int f2 = fid - 9472;
            int ki = f2 & 1; int wv = (f2 >> 1) & 3; int wg = f2 >> 3;
            int k = wv * 64 + ki * 32 + quad * 8 + j;
            if (n16 < 8) v = Wfc1[(wg * 8 + n16) * 256 + k];
        }
        bf16_t bb = (bf16_t)v;
        pk[j] = __builtin_bit_cast(unsigned short, bb);
    }
    *((u16x8*)(ws + OFF_FRAG) + (size_t)fid * 64 + lane) = pk;
}

// ---------------- persistent recurrence kernel (flag-free data-flow protocol) ----------------
// grid = 256 WGs: blockIdx = g*64 + wg. No barriers between WGs: consumers spin-load
// exchange slabs until non-poison; producers store h directly (2B per thread, earliest
// possible signal). Owners re-poison regions one phase after a poll-pass proves all
// readers are done; a vmcnt(0) before each phase's fresh store drains poisons so no
// consumer can ever accept 2-step-stale data.
__launch_bounds__(256, 1)
__global__ void k_rnn(const float* __restrict__ x, const float* __restrict__ c1i,
                      const float* __restrict__ c2i, const float* __restrict__ bfc1,
                      const float* __restrict__ b1, const float* __restrict__ b2g,
                      const float* __restrict__ bfc2, uint8_t* __restrict__ ws,
                      float* __restrict__ out) {
    const int wg = blockIdx.x & 63;
    const int g = blockIdx.x >> 6;
    const int tid = threadIdx.x;
    const int wave = tid >> 6, lane = tid & 63;
    const int quad = lane >> 4, row16 = lane & 15;
    const int brow = g * 16 + row16;

    bf16_t* pg = (bf16_t*)(ws + OFF_PG);
    bf16_t* h1b = (bf16_t*)(ws + OFF_H1);
    bf16_t* h2b = (bf16_t*)(ws + OFF_H2);
    bf16_t* outb = (bf16_t*)(ws + OFF_OUT);
    const float* b1p = (const float*)(ws + OFF_B1P);
    const u16x8* heap = (const u16x8*)(ws + OFF_FRAG);

    // ---- load all weight fragments into registers (stationary for all 2048 steps) ----
    bf16x8 fr2[16], fr3[16], fr1[5], fr10[2];
    const int wslot = wg * 4 + wave;
#pragma unroll
    for (int f = 0; f < 16; ++f)
        fr2[f] = __builtin_bit_cast(bf16x8, heap[(size_t)(FR_S2 + wslot * 16 + f) * 64 + lane]);
#pragma unroll
    for (int f = 0; f < 16; ++f)
        fr3[f] = __builtin_bit_cast(bf16x8, heap[(size_t)(FR_S3 + wslot * 16 + f) * 64 + lane]);
#pragma unroll
    for (int f = 0; f < 5; ++f)
        fr1[f] = __builtin_bit_cast(bf16x8, heap[(size_t)(FR_S1 + wslot * 5 + f) * 64 + lane]);
#pragma unroll
    for (int f = 0; f < 2; ++f)
        fr10[f] = __builtin_bit_cast(bf16x8, heap[(size_t)(FR_S1T0 + wslot * 2 + f) * 64 + lane]);

    // double-buffered reduction scratch (parity: P1/P3 use [t&1], P2 uses [1-(t&1)])
    __shared__ float red[2][4][2][16][17];  // +1 pad breaks quad aliasing

    const int rrow = tid >> 4, rc = tid & 15;
    const float bias2_a = b1[(rc >> 3) * 512 + wg * 8 + (rc & 7)];
    const float bias2_b = b1[(2 + (rc >> 3)) * 512 + wg * 8 + (rc & 7)];
    const float bias3_a = b2g[(rc >> 3) * 512 + wg * 8 + (rc & 7)];
    const float bias3_b = b2g[(2 + (rc >> 3)) * 512 + wg * 8 + (rc & 7)];
    const float bias1 = (rc < 8) ? b1p[wg * 8 + rc] : ((rc < 10) ? bfc2[wg * 2 + rc - 8] : 0.f);
    const float bias1t0 = (rc < 8) ? bfc1[wg * 8 + rc] : 0.f;

    // my exchange slot (owner of slab wg, rows of group g): element addr offset
    const size_t myoff = XIDX(wg, g * 16 + rrow) + rc;  // valid when rc<8

    // cell state in registers for the whole sequence (rc<8 threads own one cell)
    float c1r = 0.f, c2r = 0.f;
    if (rc < 8) {
        c1r = c1i[(size_t)(g * 16 + rrow) * H_ + wg * 8 + rc];
        c2r = c2i[(size_t)(g * 16 + rrow) * H_ + wg * 8 + rc];
    }

    bf16x8 xpre[4];  // x(t) bf16 prefetch, wave0 only

#pragma clang loop unroll(disable)
    for (int t = 0; t <= S_; ++t) {
        const int cbuf = t & 1, pbuf = cbuf ^ 1;

        // ============ P1: out = relu([x_t | h2(t-1)] @ W1') ; gen(t-1) = extra cols ============
        {
            f32x4 acc = {0.f, 0.f, 0.f, 0.f};
            if (t == 0) {
#pragma unroll
                for (int ki = 0; ki < 2; ++ki) {
                    int k = wave * 64 + ki * 32 + quad * 8;
                    bf16x8 a;
                    if (k < 128) {
                        const float* xp = x + ((size_t)brow * S_) * F_ + k;
                        f32x4 x0 = *(const f32x4*)xp, x1 = *(const f32x4*)(xp + 4);
#pragma unroll
                        for (int i = 0; i < 4; ++i) { a[i] = (bf16_t)x0[i]; a[4 + i] = (bf16_t)x1[i]; }
                    } else {
                        a = *(const bf16x8*)(pg + (size_t)brow * 128 + (k - 128));
                    }
                    acc = __builtin_amdgcn_mfma_f32_16x16x32_bf16(a, fr10[ki], acc, 0, 0, 0);
                }
            } else {
                const bf16_t* h2p = h2b + (size_t)pbuf * BH;  // h2(t-1): fresh from P3(t-1)
                bf16x8 aa[5];
#pragma unroll
                for (int ki = 0; ki < 5; ++ki) {
                    if (wave == 0 && ki < 4) aa[ki] = xpre[ki];
                    else {
                        int s = (wave * 160 + ki * 32 + quad * 8 - 128) >> 3;
                        aa[ki] = ld_slab(h2p + XIDX(s, brow));
                    }
                }
#pragma unroll
                for (int ki = 0; ki < 5; ++ki) {
                    if (!(wave == 0 && ki < 4)) {
                        int s = (wave * 160 + ki * 32 + quad * 8 - 128) >> 3;
                        const bf16_t* p = h2p + XIDX(s, brow);
                        while (!__all(ok8(aa[ki]))) aa[ki] = ld_slab(p);  // data IS the flag
                    }
                    acc = __builtin_amdgcn_mfma_f32_16x16x32_bf16(aa[ki], fr1[ki], acc, 0, 0, 0);
                }
            }
#pragma unroll
            for (int i = 0; i < 4; ++i) red[cbuf][wave][0][quad * 4 + i][row16] = acc[i];
            __syncthreads();
            // poll-pass proof: h2(t-1) fresh => all P3(t-1)/P1(t-1) readers of h2b[cbuf]'s
            // old content are done -> poison h2b[cbuf] (rewritten at P3(t))
            if (t < S_ && rc < 8) st_poison(h2b + (size_t)cbuf * BH + myoff);
            float v = red[cbuf][0][0][rrow][rc] + red[cbuf][1][0][rrow][rc] +
                      red[cbuf][2][0][rrow][rc] + red[cbuf][3][0][rrow][rc];
            if (t < S_) {
                asm volatile("s_waitcnt vmcnt(0)" ::: "memory");  // drain poison before fresh
                if (rc < 8) {
                    float vv = fmaxf(v + (t == 0 ? bias1t0 : bias1), 0.f);
                    st_bf16(outb + myoff, vv);
                }
            }
            if (t > 0 && rc >= 8 && rc < 10) {  // gen(t-1) -> d_out (fp32), off critical path
                out[(size_t)(g * 16 + rrow) * (S_ * F_) + (size_t)(t - 1) * F_ + wg * 2 + (rc - 8)] =
                    v + bias1;
            }
        }
        if (t == S_) break;  // last gen written; done

        // ============ P2: LSTM1 gates = [out(t) | h1(t-1)] @ W ; update c1, h1n ============
        {
            f32x4 acc0 = {0.f, 0.f, 0.f, 0.f}, acc1 = {0.f, 0.f, 0.f, 0.f};
            const bf16_t* src = (wave < 2) ? outb : (h1b + (size_t)pbuf * BH);
            const int sb = (wave & 1) * 32;
            bf16x8 aa[8];
#pragma unroll
            for (int ki = 0; ki < 8; ++ki)
                aa[ki] = ld_slab(src + XIDX(sb + ki * 4 + quad, brow));
#pragma unroll
            for (int ki = 0; ki < 8; ++ki) {
                const bf16_t* p = src + XIDX(sb + ki * 4 + quad, brow);
                while (!__all(ok8(aa[ki]))) aa[ki] = ld_slab(p);
                acc0 = __builtin_amdgcn_mfma_f32_16x16x32_bf16(aa[ki], fr2[ki * 2 + 0], acc0, 0, 0, 0);
                acc1 = __builtin_amdgcn_mfma_f32_16x16x32_bf16(aa[ki], fr2[ki * 2 + 1], acc1, 0, 0, 0);
            }
#pragma unroll
            for (int i = 0; i < 4; ++i) {
                red[pbuf][wave][0][quad * 4 + i][row16] = acc0[i];
                red[pbuf][wave][1][quad * 4 + i][row16] = acc1[i];
            }
            __syncthreads();
            float v0 = red[pbuf][0][0][rrow][rc] + red[pbuf][1][0][rrow][rc] +
                       red[pbuf][2][0][rrow][rc] + red[pbuf][3][0][rrow][rc] + bias2_a;
            float v1 = red[pbuf][0][1][rrow][rc] + red[pbuf][1][1][rrow][rc] +
                       red[pbuf][2][1][rrow][rc] + red[pbuf][3][1][rrow][rc] + bias2_b;
            float f0 = __shfl_down(v0, 8);  // f gate for rc<8
            float f1 = __shfl_down(v1, 8);  // o gate for rc<8
            if (rc < 8) {
                float cn = sigm(f0) * c1r + sigm(v0) * tanh_(v1);
                c1r = cn;
                float h = sigm(f1) * tanh_(cn);
                st_bf16(h1b + (size_t)cbuf * BH + myoff, h);  // fresh h1(t)
                if (t == S_ - 1) {
                    out[HO1 + (size_t)(g * 16 + rrow) * H_ + wg * 8 + rc] = h;
                    out[CO1 + (size_t)(g * 16 + rrow) * H_ + wg * 8 + rc] = cn;
                }
            }
        }

        // ============ P3: LSTM2 gates = [h1n(t) | h2(t-1)] @ W ; update c2, h2n ============
        {
            f32x4 acc0 = {0.f, 0.f, 0.f, 0.f}, acc1 = {0.f, 0.f, 0.f, 0.f};
            const bf16_t* src = (wave < 2) ? (h1b + (size_t)cbuf * BH) : (h2b + (size_t)pbuf * BH);
            const int sb = (wave & 1) * 32;
            bf16x8 aa[8];
#pragma unroll
            for (int ki = 0; ki < 8; ++ki)
                aa[ki] = ld_slab(src + XIDX(sb + ki * 4 + quad, brow));
#pragma unroll
            for (int ki = 0; ki < 8; ++ki) {
                const bf16_t* p = src + XIDX(sb + ki * 4 + quad, brow);
                while (!__all(ok8(aa[ki]))) aa[ki] = ld_slab(p);
                acc0 = __builtin_amdgcn_mfma_f32_16x16x32_bf16(aa[ki], fr3[ki * 2 + 0], acc0, 0, 0, 0);
                acc1 = __builtin_amdgcn_mfma_f32_16x16x32_bf16(aa[ki], fr3[ki * 2 + 1], acc1, 0, 0, 0);
            }
#pragma unroll
            for (int i = 0; i < 4; ++i) {
                red[cbuf][wave][0][quad * 4 + i][row16] = acc0[i];
                red[cbuf][wave][1][quad * 4 + i][row16] = acc1[i];
            }
            __syncthreads();
            // poll-pass proof: h1(t) fresh => all P2(t) readers done.
            // -> poison h1b[pbuf] (rewritten P2(t+1)) and outb (rewritten P1(t+1))
            if (rc < 8) {
                st_poison(h1b + (size_t)pbuf * BH + myoff);
                st_poison(outb + myoff);
            }
            float v0 = red[cbuf][0][0][rrow][rc] + red[cbuf][1][0][rrow][rc] +
                       red[cbuf][2][0][rrow][rc] + red[cbuf][3][0][rrow][rc] + bias3_a;
            float v1 = red[cbuf][0][1][rrow][rc] + red[cbuf][1][1][rrow][rc] +
                       red[cbuf][2][1][rrow][rc] + red[cbuf][3][1][rrow][rc] + bias3_b;
            float f0 = __shfl_down(v0, 8);
            float f1 = __shfl_down(v1, 8);
            asm volatile("s_waitcnt vmcnt(0)" ::: "memory");  // drain poisons before fresh h2
            if (rc < 8) {
                float cn = sigm(f0) * c2r + sigm(v0) * tanh_(v1);
                c2r = cn;
                float h = sigm(f1) * tanh_(cn);
                st_bf16(h2b + (size_t)cbuf * BH + myoff, h);  // fresh h2(t)
                if (t == S_ - 1) {
                    out[HO2 + (size_t)(g * 16 + rrow) * H_ + wg * 8 + rc] = h;
                    out[CO2 + (size_t)(g * 16 + rrow) * H_ + wg * 8 + rc] = cn;
                }
            }
        }
        // prefetch x(t+1) (plain cached loads, off critical path)
        if (wave == 0) {
            const int tn = (t + 1 < S_) ? (t + 1) : (S_ - 1);
            const float* xp = x + ((size_t)brow * S_ + tn) * F_ + quad * 8;
#pragma unroll
            for (int ki = 0; ki < 4; ++ki) {
                f32x4 x0 = *(const f32x4*)(xp + ki * 32);
                f32x4 x1 = *(const f32x4*)(xp + ki * 32 + 4);
                bf16x8 a;
#pragma unroll
                for (int i = 0; i < 4; ++i) { a[i] = (bf16_t)x0[i]; a[4 + i] = (bf16_t)x1[i]; }
                xpre[ki] = a;
            }
        }
    }
}

extern "C" void kernel_launch(void* const* d_in, const int* in_sizes, int n_in, void* d_out,
                              int out_size, void* d_ws, size_t ws_size, hipStream_t stream) {
    const float* x = (const float*)d_in[0];
    const float* pg0 = (const float*)d_in[1];
    const float* h1i = (const float*)d_in[2];
    const float* c1i = (const float*)d_in[3];
    const float* h2i = (const float*)d_in[4];
    const float* c2i = (const float*)d_in[5];
    const float* Wfc1 = (const float*)d_in[6];
    const float* bfc1 = (const float*)d_in[7];
    const float* Wih1 = (const float*)d_in[8];
    const float* Whh1 = (const float*)d_in[9];
    const float* b1 = (const float*)d_in[10];
    const float* Wih2 = (const float*)d_in[11];
    const float* Whh2 = (const float*)d_in[12];
    const float* b2g = (const float*)d_in[13];
    const float* Wfc2 = (const float*)d_in[14];
    const float* bfc2 = (const float*)d_in[15];
    uint8_t* ws = (uint8_t*)d_ws;
    float* out = (float*)d_out;

    k_init<<<dim3(128), dim3(256), 0, stream>>>(pg0, h1i, h2i, ws);
    k_fuse<<<dim3(512), dim3(128), 0, stream>>>(Wfc1, bfc1, Wfc2, bfc2, ws);
    k_frags<<<dim3(2496), dim3(256), 0, stream>>>(Wfc1, Wih1, Whh1, Wih2, Whh2, Wfc2, ws);
    k_rnn<<<dim3(256), dim3(256), 0, stream>>>(x, c1i, c2i, bfc1, b1, b2g, bfc2, ws, out);
}

// Round 6
// 21829.240 us; speedup vs baseline: 1.5021x; 1.2699x over previous
//
#include <hip/hip_runtime.h>
#include <cstdint>
#include <cstddef>

// Problem constants
#define B_ 64
#define S_ 2048
#define F_ 128
#define H_ 512
#define HO1 16777216ull
#define CO1 16809984ull
#define HO2 16842752ull
#define CO2 16875520ull
#define BH (B_ * H_)

typedef __bf16 bf16_t;
typedef __attribute__((ext_vector_type(8))) __bf16 bf16x8;
typedef __attribute__((ext_vector_type(4))) float f32x4;
typedef __attribute__((ext_vector_type(8))) unsigned short u16x8;
typedef __attribute__((ext_vector_type(4))) unsigned int u32x4;

// ---- workspace layout (bytes) ----
#define OFF_PG    2048ull     // prev_gen0 bf16 [64][128]
#define OFF_H1    18432ull    // h1 tagged u32, slab-packed [2 parity][64 slabs][64 rows][8]
#define OFF_H2    280576ull   // h2 tagged u32 (same shape)
#define OFF_OUT   542720ull   // fc1 'out' tagged u32 [64 slabs][64 rows][8]
#define OFF_B1P   673792ull   // fused bias1' fp32 [512]
#define OFF_WF    675840ull   // Wfused fp32 [512][512]
#define OFF_FRAG  1724416ull  // fragment heap (9984 frags x 1KiB)
#define FR_S2   0
#define FR_S3   4096
#define FR_S1   8192
#define FR_S1T0 9472
#define FR_TOTAL 9984

// slab-packed tagged layout: u32-element offset of (slab=col/8, row b); +j for col%8
#define TIDX(s, b) ((size_t)(((s) * 64 + (b)) * 8))

__device__ __forceinline__ float sigm(float x) { return 1.f / (1.f + __expf(-x)); }
__device__ __forceinline__ float tanh_(float x) { return 2.f / (1.f + __expf(-2.f * x)) - 1.f; }

// ---- epoch-tagged cell: u32 = (bf16 bits << 16) | (timestep tag). 4B store is atomic,
// so value+tag never tear. Tags: t (0..2047) for step-t data, 0xFFFF for initial (t=-1),
// 0xFFFE for never-written parity (never queried). Exact-match polling => no stale accept.
__device__ __forceinline__ void tag_store(unsigned int* p, float v, unsigned int tag) {
    bf16_t b = (bf16_t)v;
    unsigned int u = ((unsigned int)__builtin_bit_cast(unsigned short, b) << 16) | tag;
    __hip_atomic_store(p, u, __ATOMIC_RELAXED, __HIP_MEMORY_SCOPE_AGENT);
}

// poll one 8-element fragment (8 u32 = 32B, two dwordx4) until all tags match, then
// pack the 8 high-halves into a bf16x8. Cache-bypassing loads (sc0 sc1) as validated
// in round-1's passing run. Stale operands pass on the first iteration.
__device__ __forceinline__ bf16x8 poll_frag(const unsigned int* p, unsigned int tag) {
    u32x4 a, b;
    while (true) {
        asm volatile("global_load_dwordx4 %0, %2, off sc0 sc1\n\t"
                     "global_load_dwordx4 %1, %3, off sc0 sc1\n\t"
                     "s_waitcnt vmcnt(0)"
                     : "=&v"(a), "=&v"(b)
                     : "v"(p), "v"(p + 4)
                     : "memory");
        unsigned int m = (a[0] ^ tag) | (a[1] ^ tag) | (a[2] ^ tag) | (a[3] ^ tag) |
                         (b[0] ^ tag) | (b[1] ^ tag) | (b[2] ^ tag) | (b[3] ^ tag);
        if (__all((m & 0xFFFFu) == 0u)) break;
    }
    u32x4 o;
    o[0] = (a[0] >> 16) | (a[1] & 0xFFFF0000u);
    o[1] = (a[2] >> 16) | (a[3] & 0xFFFF0000u);
    o[2] = (b[0] >> 16) | (b[1] & 0xFFFF0000u);
    o[3] = (b[2] >> 16) | (b[3] & 0xFFFF0000u);
    return __builtin_bit_cast(bf16x8, o);
}

// ---------------- prep: init tagged buffers + small buffers ----------------
__global__ void k_init(const float* __restrict__ pg0, const float* __restrict__ h1i,
                       const float* __restrict__ h2i, uint8_t* __restrict__ ws) {
    int idx = blockIdx.x * 256 + threadIdx.x;
    if (idx < B_ * F_) ((bf16_t*)(ws + OFF_PG))[idx] = (bf16_t)pg0[idx];
    if (idx < B_ * H_) {
        int b = idx >> 9, col = idx & 511;
        size_t d = TIDX(col >> 3, b) + (col & 7);
        unsigned int* h1 = (unsigned int*)(ws + OFF_H1);
        unsigned int* h2 = (unsigned int*)(ws + OFF_H2);
        unsigned int* ob = (unsigned int*)(ws + OFF_OUT);
        bf16_t v1 = (bf16_t)h1i[idx], v2 = (bf16_t)h2i[idx];
        h1[d] = 0xFFFEu;  // parity 0: never-queried tag
        h1[BH + d] = ((unsigned int)__builtin_bit_cast(unsigned short, v1) << 16) | 0xFFFFu;
        h2[d] = 0xFFFEu;
        h2[BH + d] = ((unsigned int)__builtin_bit_cast(unsigned short, v2) << 16) | 0xFFFFu;
        ob[d] = 0xFFFEu;
    }
}

// ---------------- prep: Wfused = W_fc1[:,128:256] @ W_fc2  (and bias1') ----------------
__global__ void k_fuse(const float* __restrict__ Wfc1, const float* __restrict__ bfc1,
                       const float* __restrict__ Wfc2, const float* __restrict__ bfc2,
                       uint8_t* __restrict__ ws) {
    int o = blockIdx.x;      // 0..511
    int t = threadIdx.x;     // 0..127
    __shared__ float wrow[128];
    wrow[t] = Wfc1[o * 256 + 128 + t];
    __syncthreads();
    float* WF = (float*)(ws + OFF_WF);
    f32x4 s = {0.f, 0.f, 0.f, 0.f};
    for (int m = 0; m < 128; ++m) {
        f32x4 b = *(const f32x4*)(Wfc2 + m * 512 + t * 4);
        float w = wrow[m];
        s[0] += w * b[0]; s[1] += w * b[1]; s[2] += w * b[2]; s[3] += w * b[3];
    }
    *(f32x4*)(WF + o * 512 + t * 4) = s;
    if (t == 0) {
        float sb = bfc1[o];
        for (int m = 0; m < 128; ++m) sb += wrow[m] * bfc2[m];
        ((float*)(ws + OFF_B1P))[o] = sb;
    }
}

// ---------------- prep: build MFMA B-fragments for all stages ----------------
__global__ void k_frags(const float* __restrict__ Wfc1, const float* __restrict__ Wih1,
                        const float* __restrict__ Whh1, const float* __restrict__ Wih2,
                        const float* __restrict__ Whh2, const float* __restrict__ Wfc2,
                        uint8_t* __restrict__ ws) {
    int gid = blockIdx.x * 256 + threadIdx.x;  // exactly FR_TOTAL*64 threads
    int fid = gid >> 6;
    int lane = gid & 63;
    int n16 = lane & 15, quad = lane >> 4;
    const float* WF = (const float*)(ws + OFF_WF);
    u16x8 pk;
#pragma unroll
    for (int j = 0; j < 8; ++j) {
        float v = 0.f;
        if (fid < 4096) {  // stage2 (LSTM1): in=[out|h1] K=1024, 32 gate-cols per WG
            int tl = fid & 1, ki = (fid >> 1) & 7, wv = (fid >> 4) & 3, wg = fid >> 6;
            int n32 = tl * 16 + n16; int j8 = n32 & 7; int gate = n32 >> 3;
            int R = gate * 512 + wg * 8 + j8;
            int k = wv * 256 + ki * 32 + quad * 8 + j;
            v = (k < 512) ? Wih1[R * 512 + k] : Whh1[R * 512 + k - 512];
        } else if (fid < 8192) {  // stage3 (LSTM2): in=[h1n|h2]
            int f2 = fid - 4096;
            int tl = f2 & 1, ki = (f2 >> 1) & 7, wv = (f2 >> 4) & 3, wg = f2 >> 6;
            int n32 = tl * 16 + n16; int j8 = n32 & 7; int gate = n32 >> 3;
            int R = gate * 512 + wg * 8 + j8;
            int k = wv * 256 + ki * 32 + quad * 8 + j;
            v = (k < 512) ? Wih2[R * 512 + k] : Whh2[R * 512 + k - 512];
        } else if (fid < 9472) {  // stage1 fused (t>=1): in=[x|h2p] K=640, cols=[out(8)|gen(2)|pad]
            int f2 = fid - 8192;
            int ki = f2 % 5; int wv = (f2 / 5) & 3; int wg = f2 / 20;
            int k = wv * 160 + ki * 32 + quad * 8 + j;
            if (n16 < 8) {
                int o = wg * 8 + n16;
                v = (k < 128) ? Wfc1[o * 256 + k] : WF[o * 512 + (k - 128)];
            } else if (n16 < 10) {
                int m = wg * 2 + (n16 - 8);
                v = (k < 128) ? 0.f : Wfc2[m * 512 + (k - 128)];
            }
        } else {  // stage1 at t==0: in=[x0|prev_gen0] K=256, W_fc1 direct
            int f2 = fid - 9472;
            int ki = f2 & 1; int wv = (f2 >> 1) & 3; int wg = f2 >> 3;
            int k = wv * 64 + ki * 32 + quad * 8 + j;
            if (n16 < 8) v = Wfc1[(wg * 8 + n16) * 256 + k];
        }
        bf16_t bb = (bf16_t)v;
        pk[j] = __builtin_bit_cast(unsigned short, bb);
    }
    *((u16x8*)(ws + OFF_FRAG) + (size_t)fid * 64 + lane) = pk;
}

// ---------------- persistent recurrence kernel: tag-polled dataflow ----------------
// grid = 256 WGs (validated co-resident config): blockIdx = g*64 + wg, g: 4 batch groups
// of 16 rows, wg: 64 column-WGs. NO inter-WG barriers/flags: producers tag_store their
// cells; consumers poll_frag until the timestep tag matches. Overwrite safety is by
// data-dependence transitivity (a WG writes h1(t) only after reading out(t) from all WGs,
// which implies all WGs finished reading h1(t-2) — the content being overwritten).
__launch_bounds__(256, 1)
__global__ void k_rnn(const float* __restrict__ x, const float* __restrict__ c1i,
                      const float* __restrict__ c2i, const float* __restrict__ bfc1,
                      const float* __restrict__ b1, const float* __restrict__ b2g,
                      const float* __restrict__ bfc2, uint8_t* __restrict__ ws,
                      float* __restrict__ out) {
    const int wg = blockIdx.x & 63;
    const int g = blockIdx.x >> 6;
    const int tid = threadIdx.x;
    const int wave = tid >> 6, lane = tid & 63;
    const int quad = lane >> 4, row16 = lane & 15;
    const int brow = g * 16 + row16;

    bf16_t* pg = (bf16_t*)(ws + OFF_PG);
    unsigned int* h1t = (unsigned int*)(ws + OFF_H1);
    unsigned int* h2t = (unsigned int*)(ws + OFF_H2);
    unsigned int* outt = (unsigned int*)(ws + OFF_OUT);
    const float* b1p = (const float*)(ws + OFF_B1P);
    const u16x8* heap = (const u16x8*)(ws + OFF_FRAG);

    // ---- stationary weight fragments in registers (all 2048 steps) ----
    bf16x8 fr2[16], fr3[16], fr1[5], fr10[2];
    const int wslot = wg * 4 + wave;
#pragma unroll
    for (int f = 0; f < 16; ++f)
        fr2[f] = __builtin_bit_cast(bf16x8, heap[(size_t)(FR_S2 + wslot * 16 + f) * 64 + lane]);
#pragma unroll
    for (int f = 0; f < 16; ++f)
        fr3[f] = __builtin_bit_cast(bf16x8, heap[(size_t)(FR_S3 + wslot * 16 + f) * 64 + lane]);
#pragma unroll
    for (int f = 0; f < 5; ++f)
        fr1[f] = __builtin_bit_cast(bf16x8, heap[(size_t)(FR_S1 + wslot * 5 + f) * 64 + lane]);
#pragma unroll
    for (int f = 0; f < 2; ++f)
        fr10[f] = __builtin_bit_cast(bf16x8, heap[(size_t)(FR_S1T0 + wslot * 2 + f) * 64 + lane]);

    // reduction scratch, double-buffered by phase parity -> exactly 1 syncthreads/phase
    __shared__ float red[2][4][2][16][17];  // +1 pad breaks quad aliasing

    const int rrow = tid >> 4, rc = tid & 15;
    const float bias2_a = b1[(rc >> 3) * 512 + wg * 8 + (rc & 7)];
    const float bias2_b = b1[(2 + (rc >> 3)) * 512 + wg * 8 + (rc & 7)];
    const float bias3_a = b2g[(rc >> 3) * 512 + wg * 8 + (rc & 7)];
    const float bias3_b = b2g[(2 + (rc >> 3)) * 512 + wg * 8 + (rc & 7)];
    const float bias1 = (rc < 8) ? b1p[wg * 8 + rc] : ((rc < 10) ? bfc2[wg * 2 + rc - 8] : 0.f);
    const float bias1t0 = (rc < 8) ? bfc1[wg * 8 + rc] : 0.f;

    const size_t myoff = TIDX(wg, g * 16 + rrow) + rc;  // owner cell (valid when rc<8)

    // cell state in registers for the whole sequence (rc<8 threads own one cell)
    float c1r = 0.f, c2r = 0.f;
    if (rc < 8) {
        c1r = c1i[(size_t)(g * 16 + rrow) * H_ + wg * 8 + rc];
        c2r = c2i[(size_t)(g * 16 + rrow) * H_ + wg * 8 + rc];
    }

    bf16x8 xpre[4];  // x(t) bf16 prefetch, wave0 only

#pragma clang loop unroll(disable)
    for (int t = 0; t <= S_; ++t) {
        const int cbuf = t & 1, pbuf = cbuf ^ 1;
        const unsigned int tgc = (unsigned int)t & 0xFFFFu;          // tag of step-t data
        const unsigned int tgp = (unsigned int)(t - 1) & 0xFFFFu;    // tag of step-(t-1) data

        // ============ P1: out = relu([x_t | h2(t-1)] @ W1') ; gen(t-1) = extra cols ============
        {
            f32x4 acc = {0.f, 0.f, 0.f, 0.f};
            if (t == 0) {
#pragma unroll
                for (int ki = 0; ki < 2; ++ki) {
                    int k = wave * 64 + ki * 32 + quad * 8;
                    bf16x8 a;
                    if (k < 128) {
                        const float* xp = x + ((size_t)brow * S_) * F_ + k;
                        f32x4 x0 = *(const f32x4*)xp, x1 = *(const f32x4*)(xp + 4);
#pragma unroll
                        for (int i = 0; i < 4; ++i) { a[i] = (bf16_t)x0[i]; a[4 + i] = (bf16_t)x1[i]; }
                    } else {
                        a = *(const bf16x8*)(pg + (size_t)brow * 128 + (k - 128));
                    }
                    acc = __builtin_amdgcn_mfma_f32_16x16x32_bf16(a, fr10[ki], acc, 0, 0, 0);
                }
            } else {
                const unsigned int* h2p = h2t + (size_t)pbuf * BH;  // h2(t-1), tag t-1
#pragma unroll
                for (int ki = 0; ki < 5; ++ki) {
                    bf16x8 a;
                    if (wave == 0 && ki < 4) a = xpre[ki];
                    else {
                        int s = (wave * 160 + ki * 32 + quad * 8 - 128) >> 3;
                        a = poll_frag(h2p + TIDX(s, brow), tgp);
                    }
                    acc = __builtin_amdgcn_mfma_f32_16x16x32_bf16(a, fr1[ki], acc, 0, 0, 0);
                }
            }
#pragma unroll
            for (int i = 0; i < 4; ++i) red[cbuf][wave][0][quad * 4 + i][row16] = acc[i];
            __syncthreads();
            float v = red[cbuf][0][0][rrow][rc] + red[cbuf][1][0][rrow][rc] +
                      red[cbuf][2][0][rrow][rc] + red[cbuf][3][0][rrow][rc];
            if (t < S_ && rc < 8) {  // fresh out(t): store first — everyone waits on it
                float vv = fmaxf(v + (t == 0 ? bias1t0 : bias1), 0.f);
                tag_store(outt + myoff, vv, tgc);
            }
            if (t > 0 && rc >= 8 && rc < 10) {  // gen(t-1) -> d_out (fp32), off critical path
                out[(size_t)(g * 16 + rrow) * (S_ * F_) + (size_t)(t - 1) * F_ + wg * 2 + (rc - 8)] =
                    v + bias1;
            }
        }
        if (t == S_) break;  // last gen written; done

        // ============ P2: LSTM1 gates = [out(t) | h1(t-1)] @ W ; update c1, h1n ============
        {
            f32x4 acc0 = {0.f, 0.f, 0.f, 0.f}, acc1 = {0.f, 0.f, 0.f, 0.f};
            const unsigned int* src;
            unsigned int tg2;
            if (wave < 2) { src = outt; tg2 = tgc; }                       // fresh
            else { src = h1t + (size_t)pbuf * BH; tg2 = tgp; }             // stale
            const int sb = (wave & 1) * 32;
#pragma unroll
            for (int ki = 0; ki < 8; ++ki) {
                bf16x8 a = poll_frag(src + TIDX(sb + ki * 4 + quad, brow), tg2);
                acc0 = __builtin_amdgcn_mfma_f32_16x16x32_bf16(a, fr2[ki * 2 + 0], acc0, 0, 0, 0);
                acc1 = __builtin_amdgcn_mfma_f32_16x16x32_bf16(a, fr2[ki * 2 + 1], acc1, 0, 0, 0);
            }
#pragma unroll
            for (int i = 0; i < 4; ++i) {
                red[pbuf][wave][0][quad * 4 + i][row16] = acc0[i];
                red[pbuf][wave][1][quad * 4 + i][row16] = acc1[i];
            }
            __syncthreads();
            float v0 = red[pbuf][0][0][rrow][rc] + red[pbuf][1][0][rrow][rc] +
                       red[pbuf][2][0][rrow][rc] + red[pbuf][3][0][rrow][rc] + bias2_a;  // i | f
            float v1 = red[pbuf][0][1][rrow][rc] + red[pbuf][1][1][rrow][rc] +
                       red[pbuf][2][1][rrow][rc] + red[pbuf][3][1][rrow][rc] + bias2_b;  // g | o
            float f0 = __shfl_down(v0, 8);  // f gate for rc<8
            float f1 = __shfl_down(v1, 8);  // o gate for rc<8
            if (rc < 8) {
                float cn = sigm(f0) * c1r + sigm(v0) * tanh_(v1);
                c1r = cn;
                float h = sigm(f1) * tanh_(cn);
                tag_store(h1t + (size_t)cbuf * BH + myoff, h, tgc);  // fresh h1(t)
                if (t == S_ - 1) {
                    out[HO1 + (size_t)(g * 16 + rrow) * H_ + wg * 8 + rc] = h;
                    out[CO1 + (size_t)(g * 16 + rrow) * H_ + wg * 8 + rc] = cn;
                }
            }
        }

        // ============ P3: LSTM2 gates = [h1(t) | h2(t-1)] @ W ; update c2, h2n ============
        {
            f32x4 acc0 = {0.f, 0.f, 0.f, 0.f}, acc1 = {0.f, 0.f, 0.f, 0.f};
            const unsigned int* src;
            unsigned int tg3;
            if (wave < 2) { src = h1t + (size_t)cbuf * BH; tg3 = tgc; }    // fresh
            else { src = h2t + (size_t)pbuf * BH; tg3 = tgp; }             // stale
            const int sb = (wave & 1) * 32;
#pragma unroll
            for (int ki = 0; ki < 8; ++ki) {
                bf16x8 a = poll_frag(src + TIDX(sb + ki * 4 + quad, brow), tg3);
                acc0 = __builtin_amdgcn_mfma_f32_16x16x32_bf16(a, fr3[ki * 2 + 0], acc0, 0, 0, 0);
                acc1 = __builtin_amdgcn_mfma_f32_16x16x32_bf16(a, fr3[ki * 2 + 1], acc1, 0, 0, 0);
            }
#pragma unroll
            for (int i = 0; i < 4; ++i) {
                red[cbuf][wave][0][quad * 4 + i][row16] = acc0[i];
                red[cbuf][wave][1][quad * 4 + i][row16] = acc1[i];
            }
            __syncthreads();
            float v0 = red[cbuf][0][0][rrow][rc] + red[cbuf][1][0][rrow][rc] +
                       red[cbuf][2][0][rrow][rc] + red[cbuf][3][0][rrow][rc] + bias3_a;
            float v1 = red[cbuf][0][1][rrow][rc] + red[cbuf][1][1][rrow][rc] +
                       red[cbuf][2][1][rrow][rc] + red[cbuf][3][1][rrow][rc] + bias3_b;
            float f0 = __shfl_down(v0, 8);
            float f1 = __shfl_down(v1, 8);
            if (rc < 8) {
                float cn = sigm(f0) * c2r + sigm(v0) * tanh_(v1);
                c2r = cn;
                float h = sigm(f1) * tanh_(cn);
                tag_store(h2t + (size_t)cbuf * BH + myoff, h, tgc);  // fresh h2(t)
                if (t == S_ - 1) {
                    out[HO2 + (size_t)(g * 16 + rrow) * H_ + wg * 8 + rc] = h;
                    out[CO2 + (size_t)(g * 16 + rrow) * H_ + wg * 8 + rc] = cn;
                }
            }
        }

        // prefetch x(t+1) (plain cached loads, off critical path)
        if (wave == 0) {
            const int tn = (t + 1 < S_) ? (t + 1) : (S_ - 1);
            const float* xp = x + ((size_t)brow * S_ + tn) * F_ + quad * 8;
#pragma unroll
            for (int ki = 0; ki < 4; ++ki) {
                f32x4 x0 = *(const f32x4*)(xp + ki * 32);
                f32x4 x1 = *(const f32x4*)(xp + ki * 32 + 4);
                bf16x8 a;
#pragma unroll
                for (int i = 0; i < 4; ++i) { a[i] = (bf16_t)x0[i]; a[4 + i] = (bf16_t)x1[i]; }
                xpre[ki] = a;
            }
        }
    }
}

extern "C" void kernel_launch(void* const* d_in, const int* in_sizes, int n_in, void* d_out,
                              int out_size, void* d_ws, size_t ws_size, hipStream_t stream) {
    const float* x = (const float*)d_in[0];
    const float* pg0 = (const float*)d_in[1];
    const float* h1i = (const float*)d_in[2];
    const float* c1i = (const float*)d_in[3];
    const float* h2i = (const float*)d_in[4];
    const float* c2i = (const float*)d_in[5];
    const float* Wfc1 = (const float*)d_in[6];
    const float* bfc1 = (const float*)d_in[7];
    const float* Wih1 = (const float*)d_in[8];
    const float* Whh1 = (const float*)d_in[9];
    const float* b1 = (const float*)d_in[10];
    const float* Wih2 = (const float*)d_in[11];
    const float* Whh2 = (const float*)d_in[12];
    const float* b2g = (const float*)d_in[13];
    const float* Wfc2 = (const float*)d_in[14];
    const float* bfc2 = (const float*)d_in[15];
    uint8_t* ws = (uint8_t*)d_ws;
    float* out = (float*)d_out;

    k_init<<<dim3(128), dim3(256), 0, stream>>>(pg0, h1i, h2i, ws);
    k_fuse<<<dim3(512), dim3(128), 0, stream>>>(Wfc1, bfc1, Wfc2, bfc2, ws);
    k_frags<<<dim3(2496), dim3(256), 0, stream>>>(Wfc1, Wih1, Whh1, Wih2, Whh2, Wfc2, ws);
    k_rnn<<<dim3(256), dim3(256), 0, stream>>>(x, c1i, c2i, bfc1, b1, b2g, bfc2, ws, out);
}

// Round 7
// 15272.311 us; speedup vs baseline: 2.1471x; 1.4293x over previous
//
#include <hip/hip_runtime.h>
#include <cstdint>
#include <cstddef>

// Problem constants
#define B_ 64
#define S_ 2048
#define F_ 128
#define H_ 512
#define HO1 16777216ull
#define CO1 16809984ull
#define HO2 16842752ull
#define CO2 16875520ull
#define BH (B_ * H_)

typedef __bf16 bf16_t;
typedef __attribute__((ext_vector_type(8))) __bf16 bf16x8;
typedef __attribute__((ext_vector_type(4))) float f32x4;
typedef __attribute__((ext_vector_type(8))) unsigned short u16x8;
typedef __attribute__((ext_vector_type(4))) unsigned int u32x4;

// ---- workspace layout (bytes) ----
#define OFF_PG    2048ull     // prev_gen0 bf16 [64][128]
#define OFF_H1    18432ull    // h1 tagged u32, slab-packed [2 parity][64 slabs][64 rows][8]
#define OFF_H2    280576ull   // h2 tagged u32 (same shape)
#define OFF_OUT   542720ull   // fc1 'out' tagged u32 [64 slabs][64 rows][8]
#define OFF_B1P   673792ull   // fused bias1' fp32 [512]
#define OFF_WF    675840ull   // Wfused fp32 [512][512]
#define OFF_FRAG  1724416ull  // fragment heap (9984 frags x 1KiB)
#define FR_S2   0
#define FR_S3   4096
#define FR_S1   8192
#define FR_S1T0 9472
#define FR_TOTAL 9984

// slab-packed tagged layout: u32-element offset of (slab=col/8, row b); +j for col%8
#define TIDX(s, b) ((size_t)(((s) * 64 + (b)) * 8))

__device__ __forceinline__ float sigm(float x) { return 1.f / (1.f + __expf(-x)); }
__device__ __forceinline__ float tanh_(float x) { return 2.f / (1.f + __expf(-2.f * x)) - 1.f; }

// ---- epoch-tagged cell: u32 = (bf16 bits << 16) | (timestep tag). 4B store is atomic,
// so value+tag never tear. Tags: t (0..2047) for step-t data, 0xFFFF for initial (t=-1),
// 0xFFFE for never-written parity (never queried). Exact-match polling => no stale accept.
__device__ __forceinline__ void tag_store(unsigned int* p, float v, unsigned int tag) {
    bf16_t b = (bf16_t)v;
    unsigned int u = ((unsigned int)__builtin_bit_cast(unsigned short, b) << 16) | tag;
    __hip_atomic_store(p, u, __ATOMIC_RELAXED, __HIP_MEMORY_SCOPE_AGENT);
}

// issue-only cache-bypassing dwordx4 load (no wait — caller batches a single vmcnt(0))
__device__ __forceinline__ void ld_issue(u32x4* dst, const unsigned int* p) {
    asm volatile("global_load_dwordx4 %0, %1, off sc0 sc1" : "=v"(*dst) : "v"(p) : "memory");
}

// pack 8 tagged u32 (two dwordx4) into bf16x8 (high halves)
__device__ __forceinline__ bf16x8 pack_frag(u32x4 a, u32x4 b) {
    u32x4 o;
    o[0] = (a[0] >> 16) | (a[1] & 0xFFFF0000u);
    o[1] = (a[2] >> 16) | (a[3] & 0xFFFF0000u);
    o[2] = (b[0] >> 16) | (b[1] & 0xFFFF0000u);
    o[3] = (b[2] >> 16) | (b[3] & 0xFFFF0000u);
    return __builtin_bit_cast(bf16x8, o);
}

__device__ __forceinline__ unsigned int tag_miss(u32x4 a, u32x4 b, unsigned int tg) {
    return (a[0] ^ tg) | (a[1] ^ tg) | (a[2] ^ tg) | (a[3] ^ tg) |
           (b[0] ^ tg) | (b[1] ^ tg) | (b[2] ^ tg) | (b[3] ^ tg);
}

// single-fragment poll (P1 wave0 only — 1 fragment, serial is fine)
__device__ __forceinline__ bf16x8 poll_frag(const unsigned int* p, unsigned int tag) {
    u32x4 a, b;
    while (true) {
        ld_issue(&a, p);
        ld_issue(&b, p + 4);
        asm volatile("s_waitcnt vmcnt(0)" ::: "memory");
        if (__all((tag_miss(a, b, tag) & 0xFFFFu) == 0u)) break;
    }
    return pack_frag(a, b);
}

// ---------------- prep: init tagged buffers + small buffers ----------------
__global__ void k_init(const float* __restrict__ pg0, const float* __restrict__ h1i,
                       const float* __restrict__ h2i, uint8_t* __restrict__ ws) {
    int idx = blockIdx.x * 256 + threadIdx.x;
    if (idx < B_ * F_) ((bf16_t*)(ws + OFF_PG))[idx] = (bf16_t)pg0[idx];
    if (idx < B_ * H_) {
        int b = idx >> 9, col = idx & 511;
        size_t d = TIDX(col >> 3, b) + (col & 7);
        unsigned int* h1 = (unsigned int*)(ws + OFF_H1);
        unsigned int* h2 = (unsigned int*)(ws + OFF_H2);
        unsigned int* ob = (unsigned int*)(ws + OFF_OUT);
        bf16_t v1 = (bf16_t)h1i[idx], v2 = (bf16_t)h2i[idx];
        h1[d] = 0xFFFEu;  // parity 0: never-queried tag
        h1[BH + d] = ((unsigned int)__builtin_bit_cast(unsigned short, v1) << 16) | 0xFFFFu;
        h2[d] = 0xFFFEu;
        h2[BH + d] = ((unsigned int)__builtin_bit_cast(unsigned short, v2) << 16) | 0xFFFFu;
        ob[d] = 0xFFFEu;
    }
}

// ---------------- prep: Wfused = W_fc1[:,128:256] @ W_fc2  (and bias1') ----------------
__global__ void k_fuse(const float* __restrict__ Wfc1, const float* __restrict__ bfc1,
                       const float* __restrict__ Wfc2, const float* __restrict__ bfc2,
                       uint8_t* __restrict__ ws) {
    int o = blockIdx.x;      // 0..511
    int t = threadIdx.x;     // 0..127
    __shared__ float wrow[128];
    wrow[t] = Wfc1[o * 256 + 128 + t];
    __syncthreads();
    float* WF = (float*)(ws + OFF_WF);
    f32x4 s = {0.f, 0.f, 0.f, 0.f};
    for (int m = 0; m < 128; ++m) {
        f32x4 b = *(const f32x4*)(Wfc2 + m * 512 + t * 4);
        float w = wrow[m];
        s[0] += w * b[0]; s[1] += w * b[1]; s[2] += w * b[2]; s[3] += w * b[3];
    }
    *(f32x4*)(WF + o * 512 + t * 4) = s;
    if (t == 0) {
        float sb = bfc1[o];
        for (int m = 0; m < 128; ++m) sb += wrow[m] * bfc2[m];
        ((float*)(ws + OFF_B1P))[o] = sb;
    }
}

// ---------------- prep: build MFMA B-fragments for all stages ----------------
__global__ void k_frags(const float* __restrict__ Wfc1, const float* __restrict__ Wih1,
                        const float* __restrict__ Whh1, const float* __restrict__ Wih2,
                        const float* __restrict__ Whh2, const float* __restrict__ Wfc2,
                        uint8_t* __restrict__ ws) {
    int gid = blockIdx.x * 256 + threadIdx.x;  // exactly FR_TOTAL*64 threads
    int fid = gid >> 6;
    int lane = gid & 63;
    int n16 = lane & 15, quad = lane >> 4;
    const float* WF = (const float*)(ws + OFF_WF);
    u16x8 pk;
#pragma unroll
    for (int j = 0; j < 8; ++j) {
        float v = 0.f;
        if (fid < 4096) {  // stage2 (LSTM1): in=[out|h1] K=1024, 32 gate-cols per WG
            int tl = fid & 1, ki = (fid >> 1) & 7, wv = (fid >> 4) & 3, wg = fid >> 6;
            int n32 = tl * 16 + n16; int j8 = n32 & 7; int gate = n32 >> 3;
            int R = gate * 512 + wg * 8 + j8;
            int k = wv * 256 + ki * 32 + quad * 8 + j;
            v = (k < 512) ? Wih1[R * 512 + k] : Whh1[R * 512 + k - 512];
        } else if (fid < 8192) {  // stage3 (LSTM2): in=[h1n|h2]
            int f2 = fid - 4096;
            int tl = f2 & 1, ki = (f2 >> 1) & 7, wv = (f2 >> 4) & 3, wg = f2 >> 6;
            int n32 = tl * 16 + n16; int j8 = n32 & 7; int gate = n32 >> 3;
            int R = gate * 512 + wg * 8 + j8;
            int k = wv * 256 + ki * 32 + quad * 8 + j;
            v = (k < 512) ? Wih2[R * 512 + k] : Whh2[R * 512 + k - 512];
        } else if (fid < 9472) {  // stage1 fused (t>=1): in=[x|h2p] K=640, cols=[out(8)|gen(2)|pad]
            int f2 = fid - 8192;
            int ki = f2 % 5; int wv = (f2 / 5) & 3; int wg = f2 / 20;
            int k = wv * 160 + ki * 32 + quad * 8 + j;
            if (n16 < 8) {
                int o = wg * 8 + n16;
                v = (k < 128) ? Wfc1[o * 256 + k] : WF[o * 512 + (k - 128)];
            } else if (n16 < 10) {
                int m = wg * 2 + (n16 - 8);
                v = (k < 128) ? 0.f : Wfc2[m * 512 + (k - 128)];
            }
        } else {  // stage1 at t==0: in=[x0|prev_gen0] K=256, W_fc1 direct
            int f2 = fid - 9472;
            int ki = f2 & 1; int wv = (f2 >> 1) & 3; int wg = f2 >> 3;
            int k = wv * 64 + ki * 32 + quad * 8 + j;
            if (n16 < 8) v = Wfc1[(wg * 8 + n16) * 256 + k];
        }
        bf16_t bb = (bf16_t)v;
        pk[j] = __builtin_bit_cast(unsigned short, bb);
    }
    *((u16x8*)(ws + OFF_FRAG) + (size_t)fid * 64 + lane) = pk;
}

// ---------------- persistent recurrence kernel: tag-polled dataflow (batched polls) ----------------
// grid = 256 WGs: blockIdx = g*64 + wg. Same protocol as the passing round-6 kernel; the
// only change is issue-width: each poll iteration issues ALL fragment loads back-to-back
// (10-16 dwordx4 in flight), waits once, checks all tags -> one MALL round trip per
// iteration instead of one per fragment.
__launch_bounds__(256, 1)
__global__ void k_rnn(const float* __restrict__ x, const float* __restrict__ c1i,
                      const float* __restrict__ c2i, const float* __restrict__ bfc1,
                      const float* __restrict__ b1, const float* __restrict__ b2g,
                      const float* __restrict__ bfc2, uint8_t* __restrict__ ws,
                      float* __restrict__ out) {
    const int wg = blockIdx.x & 63;
    const int g = blockIdx.x >> 6;
    const int tid = threadIdx.x;
    const int wave = tid >> 6, lane = tid & 63;
    const int quad = lane >> 4, row16 = lane & 15;
    const int brow = g * 16 + row16;

    bf16_t* pg = (bf16_t*)(ws + OFF_PG);
    unsigned int* h1t = (unsigned int*)(ws + OFF_H1);
    unsigned int* h2t = (unsigned int*)(ws + OFF_H2);
    unsigned int* outt = (unsigned int*)(ws + OFF_OUT);
    const float* b1p = (const float*)(ws + OFF_B1P);
    const u16x8* heap = (const u16x8*)(ws + OFF_FRAG);

    // ---- stationary weight fragments in registers (all 2048 steps) ----
    bf16x8 fr2[16], fr3[16], fr1[5], fr10[2];
    const int wslot = wg * 4 + wave;
#pragma unroll
    for (int f = 0; f < 16; ++f)
        fr2[f] = __builtin_bit_cast(bf16x8, heap[(size_t)(FR_S2 + wslot * 16 + f) * 64 + lane]);
#pragma unroll
    for (int f = 0; f < 16; ++f)
        fr3[f] = __builtin_bit_cast(bf16x8, heap[(size_t)(FR_S3 + wslot * 16 + f) * 64 + lane]);
#pragma unroll
    for (int f = 0; f < 5; ++f)
        fr1[f] = __builtin_bit_cast(bf16x8, heap[(size_t)(FR_S1 + wslot * 5 + f) * 64 + lane]);
#pragma unroll
    for (int f = 0; f < 2; ++f)
        fr10[f] = __builtin_bit_cast(bf16x8, heap[(size_t)(FR_S1T0 + wslot * 2 + f) * 64 + lane]);

    // reduction scratch, double-buffered by phase parity -> exactly 1 syncthreads/phase
    __shared__ float red[2][4][2][16][17];  // +1 pad breaks quad aliasing

    const int rrow = tid >> 4, rc = tid & 15;
    const float bias2_a = b1[(rc >> 3) * 512 + wg * 8 + (rc & 7)];
    const float bias2_b = b1[(2 + (rc >> 3)) * 512 + wg * 8 + (rc & 7)];
    const float bias3_a = b2g[(rc >> 3) * 512 + wg * 8 + (rc & 7)];
    const float bias3_b = b2g[(2 + (rc >> 3)) * 512 + wg * 8 + (rc & 7)];
    const float bias1 = (rc < 8) ? b1p[wg * 8 + rc] : ((rc < 10) ? bfc2[wg * 2 + rc - 8] : 0.f);
    const float bias1t0 = (rc < 8) ? bfc1[wg * 8 + rc] : 0.f;

    const size_t myoff = TIDX(wg, g * 16 + rrow) + rc;  // owner cell (valid when rc<8)

    // cell state in registers for the whole sequence (rc<8 threads own one cell)
    float c1r = 0.f, c2r = 0.f;
    if (rc < 8) {
        c1r = c1i[(size_t)(g * 16 + rrow) * H_ + wg * 8 + rc];
        c2r = c2i[(size_t)(g * 16 + rrow) * H_ + wg * 8 + rc];
    }

    bf16x8 xpre[4];  // x(t) bf16 prefetch, wave0 only

#pragma clang loop unroll(disable)
    for (int t = 0; t <= S_; ++t) {
        const int cbuf = t & 1, pbuf = cbuf ^ 1;
        const unsigned int tgc = (unsigned int)t & 0xFFFFu;          // tag of step-t data
        const unsigned int tgp = (unsigned int)(t - 1) & 0xFFFFu;    // tag of step-(t-1) data

        // ============ P1: out = relu([x_t | h2(t-1)] @ W1') ; gen(t-1) = extra cols ============
        {
            f32x4 acc = {0.f, 0.f, 0.f, 0.f};
            if (t == 0) {
#pragma unroll
                for (int ki = 0; ki < 2; ++ki) {
                    int k = wave * 64 + ki * 32 + quad * 8;
                    bf16x8 a;
                    if (k < 128) {
                        const float* xp = x + ((size_t)brow * S_) * F_ + k;
                        f32x4 x0 = *(const f32x4*)xp, x1 = *(const f32x4*)(xp + 4);
#pragma unroll
                        for (int i = 0; i < 4; ++i) { a[i] = (bf16_t)x0[i]; a[4 + i] = (bf16_t)x1[i]; }
                    } else {
                        a = *(const bf16x8*)(pg + (size_t)brow * 128 + (k - 128));
                    }
                    acc = __builtin_amdgcn_mfma_f32_16x16x32_bf16(a, fr10[ki], acc, 0, 0, 0);
                }
            } else {
                const unsigned int* h2p = h2t + (size_t)pbuf * BH;  // h2(t-1), tag t-1
                bf16x8 aa[5];
                if (wave == 0) {
#pragma unroll
                    for (int ki = 0; ki < 4; ++ki) aa[ki] = xpre[ki];
                    aa[4] = poll_frag(h2p + TIDX(quad, brow), tgp);
                } else {
                    u32x4 fa[5], fb[5];
                    while (true) {
#pragma unroll
                        for (int ki = 0; ki < 5; ++ki) {
                            int s = (wave * 160 + ki * 32 + quad * 8 - 128) >> 3;
                            const unsigned int* p = h2p + TIDX(s, brow);
                            ld_issue(&fa[ki], p);
                            ld_issue(&fb[ki], p + 4);
                        }
                        asm volatile("s_waitcnt vmcnt(0)" ::: "memory");
                        unsigned int m = 0;
#pragma unroll
                        for (int ki = 0; ki < 5; ++ki) m |= tag_miss(fa[ki], fb[ki], tgp);
                        if (__all((m & 0xFFFFu) == 0u)) break;
                    }
#pragma unroll
                    for (int ki = 0; ki < 5; ++ki) aa[ki] = pack_frag(fa[ki], fb[ki]);
                }
#pragma unroll
                for (int ki = 0; ki < 5; ++ki)
                    acc = __builtin_amdgcn_mfma_f32_16x16x32_bf16(aa[ki], fr1[ki], acc, 0, 0, 0);
            }
#pragma unroll
            for (int i = 0; i < 4; ++i) red[cbuf][wave][0][quad * 4 + i][row16] = acc[i];
            __syncthreads();
            float v = red[cbuf][0][0][rrow][rc] + red[cbuf][1][0][rrow][rc] +
                      red[cbuf][2][0][rrow][rc] + red[cbuf][3][0][rrow][rc];
            if (t < S_ && rc < 8) {  // fresh out(t): store first — everyone waits on it
                float vv = fmaxf(v + (t == 0 ? bias1t0 : bias1), 0.f);
                tag_store(outt + myoff, vv, tgc);
            }
            if (t > 0 && rc >= 8 && rc < 10) {  // gen(t-1) -> d_out (fp32), off critical path
                out[(size_t)(g * 16 + rrow) * (S_ * F_) + (size_t)(t - 1) * F_ + wg * 2 + (rc - 8)] =
                    v + bias1;
            }
        }
        if (t == S_) break;  // last gen written; done

        // ============ P2: LSTM1 gates = [out(t) | h1(t-1)] @ W ; update c1, h1n ============
        {
            f32x4 acc0 = {0.f, 0.f, 0.f, 0.f}, acc1 = {0.f, 0.f, 0.f, 0.f};
            const unsigned int* src;
            unsigned int tg2;
            if (wave < 2) { src = outt; tg2 = tgc; }                       // fresh
            else { src = h1t + (size_t)pbuf * BH; tg2 = tgp; }             // stale
            const int sb = (wave & 1) * 32;
            u32x4 fa[8], fb[8];
            while (true) {
#pragma unroll
                for (int ki = 0; ki < 8; ++ki) {
                    const unsigned int* p = src + TIDX(sb + ki * 4 + quad, brow);
                    ld_issue(&fa[ki], p);
                    ld_issue(&fb[ki], p + 4);
                }
                asm volatile("s_waitcnt vmcnt(0)" ::: "memory");
                unsigned int m = 0;
#pragma unroll
                for (int ki = 0; ki < 8; ++ki) m |= tag_miss(fa[ki], fb[ki], tg2);
                if (__all((m & 0xFFFFu) == 0u)) break;
            }
#pragma unroll
            for (int ki = 0; ki < 8; ++ki) {
                bf16x8 a = pack_frag(fa[ki], fb[ki]);
                acc0 = __builtin_amdgcn_mfma_f32_16x16x32_bf16(a, fr2[ki * 2 + 0], acc0, 0, 0, 0);
                acc1 = __builtin_amdgcn_mfma_f32_16x16x32_bf16(a, fr2[ki * 2 + 1], acc1, 0, 0, 0);
            }
#pragma unroll
            for (int i = 0; i < 4; ++i) {
                red[pbuf][wave][0][quad * 4 + i][row16] = acc0[i];
                red[pbuf][wave][1][quad * 4 + i][row16] = acc1[i];
            }
            __syncthreads();
            float v0 = red[pbuf][0][0][rrow][rc] + red[pbuf][1][0][rrow][rc] +
                       red[pbuf][2][0][rrow][rc] + red[pbuf][3][0][rrow][rc] + bias2_a;  // i | f
            float v1 = red[pbuf][0][1][rrow][rc] + red[pbuf][1][1][rrow][rc] +
                       red[pbuf][2][1][rrow][rc] + red[pbuf][3][1][rrow][rc] + bias2_b;  // g | o
            float f0 = __shfl_down(v0, 8);  // f gate for rc<8
            float f1 = __shfl_down(v1, 8);  // o gate for rc<8
            if (rc < 8) {
                float cn = sigm(f0) * c1r + sigm(v0) * tanh_(v1);
                c1r = cn;
                float h = sigm(f1) * tanh_(cn);
                tag_store(h1t + (size_t)cbuf * BH + myoff, h, tgc);  // fresh h1(t)
                if (t == S_ - 1) {
                    out[HO1 + (size_t)(g * 16 + rrow) * H_ + wg * 8 + rc] = h;
                    out[CO1 + (size_t)(g * 16 + rrow) * H_ + wg * 8 + rc] = cn;
                }
            }
        }

        // ============ P3: LSTM2 gates = [h1(t) | h2(t-1)] @ W ; update c2, h2n ============
        {
            f32x4 acc0 = {0.f, 0.f, 0.f, 0.f}, acc1 = {0.f, 0.f, 0.f, 0.f};
            const unsigned int* src;
            unsigned int tg3;
            if (wave < 2) { src = h1t + (size_t)cbuf * BH; tg3 = tgc; }    // fresh
            else { src = h2t + (size_t)pbuf * BH; tg3 = tgp; }             // stale
            const int sb = (wave & 1) * 32;
            u32x4 fa[8], fb[8];
            while (true) {
#pragma unroll
                for (int ki = 0; ki < 8; ++ki) {
                    const unsigned int* p = src + TIDX(sb + ki * 4 + quad, brow);
                    ld_issue(&fa[ki], p);
                    ld_issue(&fb[ki], p + 4);
                }
                asm volatile("s_waitcnt vmcnt(0)" ::: "memory");
                unsigned int m = 0;
#pragma unroll
                for (int ki = 0; ki < 8; ++ki) m |= tag_miss(fa[ki], fb[ki], tg3);
                if (__all((m & 0xFFFFu) == 0u)) break;
            }
#pragma unroll
            for (int ki = 0; ki < 8; ++ki) {
                bf16x8 a = pack_frag(fa[ki], fb[ki]);
                acc0 = __builtin_amdgcn_mfma_f32_16x16x32_bf16(a, fr3[ki * 2 + 0], acc0, 0, 0, 0);
                acc1 = __builtin_amdgcn_mfma_f32_16x16x32_bf16(a, fr3[ki * 2 + 1], acc1, 0, 0, 0);
            }
#pragma unroll
            for (int i = 0; i < 4; ++i) {
                red[cbuf][wave][0][quad * 4 + i][row16] = acc0[i];
                red[cbuf][wave][1][quad * 4 + i][row16] = acc1[i];
            }
            __syncthreads();
            float v0 = red[cbuf][0][0][rrow][rc] + red[cbuf][1][0][rrow][rc] +
                       red[cbuf][2][0][rrow][rc] + red[cbuf][3][0][rrow][rc] + bias3_a;
            float v1 = red[cbuf][0][1][rrow][rc] + red[cbuf][1][1][rrow][rc] +
                       red[cbuf][2][1][rrow][rc] + red[cbuf][3][1][rrow][rc] + bias3_b;
            float f0 = __shfl_down(v0, 8);
            float f1 = __shfl_down(v1, 8);
            if (rc < 8) {
                float cn = sigm(f0) * c2r + sigm(v0) * tanh_(v1);
                c2r = cn;
                float h = sigm(f1) * tanh_(cn);
                tag_store(h2t + (size_t)cbuf * BH + myoff, h, tgc);  // fresh h2(t)
                if (t == S_ - 1) {
                    out[HO2 + (size_t)(g * 16 + rrow) * H_ + wg * 8 + rc] = h;
                    out[CO2 + (size_t)(g * 16 + rrow) * H_ + wg * 8 + rc] = cn;
                }
            }
        }

        // prefetch x(t+1) (plain cached loads, off critical path)
        if (wave == 0) {
            const int tn = (t + 1 < S_) ? (t + 1) : (S_ - 1);
            const float* xp = x + ((size_t)brow * S_ + tn) * F_ + quad * 8;
#pragma unroll
            for (int ki = 0; ki < 4; ++ki) {
                f32x4 x0 = *(const f32x4*)(xp + ki * 32);
                f32x4 x1 = *(const f32x4*)(xp + ki * 32 + 4);
                bf16x8 a;
#pragma unroll
                for (int i = 0; i < 4; ++i) { a[i] = (bf16_t)x0[i]; a[4 + i] = (bf16_t)x1[i]; }
                xpre[ki] = a;
            }
        }
    }
}

extern "C" void kernel_launch(void* const* d_in, const int* in_sizes, int n_in, void* d_out,
                              int out_size, void* d_ws, size_t ws_size, hipStream_t stream) {
    const float* x = (const float*)d_in[0];
    const float* pg0 = (const float*)d_in[1];
    const float* h1i = (const float*)d_in[2];
    const float* c1i = (const float*)d_in[3];
    const float* h2i = (const float*)d_in[4];
    const float* c2i = (const float*)d_in[5];
    const float* Wfc1 = (const float*)d_in[6];
    const float* bfc1 = (const float*)d_in[7];
    const float* Wih1 = (const float*)d_in[8];
    const float* Whh1 = (const float*)d_in[9];
    const float* b1 = (const float*)d_in[10];
    const float* Wih2 = (const float*)d_in[11];
    const float* Whh2 = (const float*)d_in[12];
    const float* b2g = (const float*)d_in[13];
    const float* Wfc2 = (const float*)d_in[14];
    const float* bfc2 = (const float*)d_in[15];
    uint8_t* ws = (uint8_t*)d_ws;
    float* out = (float*)d_out;

    k_init<<<dim3(128), dim3(256), 0, stream>>>(pg0, h1i, h2i, ws);
    k_fuse<<<dim3(512), dim3(128), 0, stream>>>(Wfc1, bfc1, Wfc2, bfc2, ws);
    k_frags<<<dim3(2496), dim3(256), 0, stream>>>(Wfc1, Wih1, Whh1, Wih2, Whh2, Wfc2, ws);
    k_rnn<<<dim3(256), dim3(256), 0, stream>>>(x, c1i, c2i, bfc1, b1, b2g, bfc2, ws, out);
}